// Round 1
// 500.887 us; speedup vs baseline: 1.0846x; 1.0846x over previous
//
#include <hip/hip_runtime.h>
#include <hip/hip_bf16.h>
#include <math.h>

// Problem constants
#define BB 8
#define LL 8192
#define DD 512
#define NROWS (BB * LL)  // 65536

// d_out layout (floats)
#define OUT_COMP   0
#define OUT_MASK   33554432
#define OUT_BHARD  33619968
#define OUT_P      33685504
#define OUT_PCOMP  33751040
#define OUT_LOSS   33816576

// ws layout (bytes)
#define WS_FIXLIST 0         // 65536*4
#define WS_FIXCNT  262144    // 4
#define WS_COUNTS  262148    // 32
#define WS_SUMP    262180    // 32
#define WS_SEL     262212    // 65536*4 -> 524356
#define WS_SSK     524416    // 65536*4
#define WS_SSQ     786560    // 65536*4
#define WS_DOT     1048704   // 65536*4
#define WS_WQH     1310848   // 512 KB each
#define WS_WQL     1835136
#define WS_WKH     2359424
#define WS_WKL     2883712   // end ~3.4 MB

#define FIX_CAP 65536
#define FIX_TAU 1e-4f

typedef __attribute__((ext_vector_type(8))) _Float16 half8;
typedef __attribute__((ext_vector_type(4))) float f32x4;

// async global->LDS, 16 B per lane; lds base wave-uniform, data lands at
// lds + lane*16 (m104/m108) -- layouts below are lane-sequential.
static __device__ __forceinline__ void ld_g2l16(const void* g, void* l) {
  __builtin_amdgcn_global_load_lds(
      (const __attribute__((address_space(1))) void*)g,
      (__attribute__((address_space(3))) void*)l, 16, 0, 0);
}

// ---------------------------------------------------------------------------
// Pass 0: split Wq,Wk into f16 hi/lo (hi = f16(w), lo = f16(w - hi)),
// fragment-chunk order: chunk c = (kt*32 + ct)*64 + kblk*16 + n holds
// W[e = ct*16+n][d = kt*32 + kblk*8 .. +8]. Also zero-inits accumulators.
// ---------------------------------------------------------------------------
__global__ __launch_bounds__(256) void wsplit(
    const float* __restrict__ Wq, const float* __restrict__ Wk,
    _Float16* __restrict__ wqh, _Float16* __restrict__ wql,
    _Float16* __restrict__ wkh, _Float16* __restrict__ wkl,
    float* __restrict__ ssk, float* __restrict__ ssq,
    float* __restrict__ dotb, int* __restrict__ fixcnt) {
  const int t = blockIdx.x * 256 + threadIdx.x;  // 0..65535
  if (t == 0) *fixcnt = 0;
  ssk[t] = 0.0f;
  ssq[t] = 0.0f;
  dotb[t] = 0.0f;

  const int m = t >> 15;         // 0 = Wq, 1 = Wk
  const int c = t & 32767;       // chunk id
  const int kt = c >> 11;
  const int ct = (c >> 6) & 31;
  const int l = c & 63;
  const int n = l & 15;
  const int kblk = l >> 4;
  const int e = ct * 16 + n;
  const int d0 = kt * 32 + kblk * 8;
  const float* src = (m ? Wk : Wq) + (long)e * 512 + d0;
  _Float16* dh = (m ? wkh : wqh) + (long)c * 8;
  _Float16* dl = (m ? wkl : wql) + (long)c * 8;
  float4 v0 = *(const float4*)src;
  float4 v1 = *(const float4*)(src + 4);
  float av[8] = {v0.x, v0.y, v0.z, v0.w, v1.x, v1.y, v1.z, v1.w};
  half8 hi, lo;
#pragma unroll
  for (int j = 0; j < 8; ++j) {
    _Float16 hh = (_Float16)av[j];
    hi[j] = hh;
    lo[j] = (_Float16)(av[j] - (float)hh);
  }
  *(half8*)dh = hi;
  *(half8*)dl = lo;
}

// ---------------------------------------------------------------------------
// FUSED GEMM: q = x*Wq^T and k = x*Wk^T in one pass. 128x128 tile, BK=32,
// 4 waves 2x2. A (x) staged ONCE per K-step, feeds both GEMMs (96 MFMA/kt).
// f16 hi/lo split, 3 pairings each (residual ~1e-5 in cos, f64 fixup covers).
// Epilogue: k-acc -> LDS (f16, stride 136 to dodge bank conflicts), then
// per-row ssq/ssk/dot partials -> atomics. Block-boundary k rows (r0-1) are
// handled via 1 MB q/k edge buffers + the edgedot kernel.
// ---------------------------------------------------------------------------
__global__ __launch_bounds__(256, 2) void gemm_fused(
    const float* __restrict__ x,
    const _Float16* __restrict__ wqh, const _Float16* __restrict__ wql,
    const _Float16* __restrict__ wkh, const _Float16* __restrict__ wkl,
    float* __restrict__ ssqOut, float* __restrict__ sskOut,
    float* __restrict__ dotOut,
    float* __restrict__ qedge, float* __restrict__ kedge) {
  __shared__ _Float16 smem[24576];  // 48 KB
  _Float16* AH = smem;              // chunks 0..511: (mbs*64 + kblk*16 + ms)
  _Float16* AL = AH + 4096;
  _Float16* BQH = AL + 4096;        // chunks: (ctl*64 + kblk*16 + n)
  _Float16* BQL = BQH + 4096;
  _Float16* BKH = BQL + 4096;
  _Float16* BKL = BKH + 4096;

  const int tid = threadIdx.x;
  const int lane = tid & 63;
  const int w = tid >> 6;
  const int wrow = w & 1, wcol = w >> 1;
  const int g = lane >> 4, n = lane & 15;
  const int bx = blockIdx.x;
  const int rb = bx >> 2, cb = bx & 3;
  const long r0 = (long)rb * 128;

  // A staging: tid = (mbs<<6)|(kblk<<4)|ms -> chunk c1=tid (row arow),
  // chunk c2=tid+256 (row arow+64). 8 consecutive floats at col akb*8.
  const int arow = ((tid >> 6) << 4) | (tid & 15);
  const int akb = (tid >> 4) & 3;
  const float* ap = x + (r0 + arow) * 512 + akb * 8;

  f32x4 accq[4][4], acck[4][4];
#pragma unroll
  for (int mb = 0; mb < 4; ++mb)
#pragma unroll
    for (int nb = 0; nb < 4; ++nb) {
      accq[mb][nb] = (f32x4){0.f, 0.f, 0.f, 0.f};
      acck[mb][nb] = (f32x4){0.f, 0.f, 0.f, 0.f};
    }

  // prefetch A for kt=0
  float4 f0 = *(const float4*)(ap);
  float4 f1 = *(const float4*)(ap + 4);
  float4 f2 = *(const float4*)(ap + 64 * 512);
  float4 f3 = *(const float4*)(ap + 64 * 512 + 4);

  for (int kt = 0; kt < 16; ++kt) {
    // --- B tiles async: Wq hi/lo + Wk hi/lo = 32 KB; wave w stages 2 KB of
    // each of the 4 buffers ---
    const long bbase = ((long)(kt * 32 + cb * 8) << 9) + w * 1024 + lane * 8;
    ld_g2l16(wqh + bbase, BQH + w * 1024);
    ld_g2l16(wqh + bbase + 512, BQH + w * 1024 + 512);
    ld_g2l16(wql + bbase, BQL + w * 1024);
    ld_g2l16(wql + bbase + 512, BQL + w * 1024 + 512);
    ld_g2l16(wkh + bbase, BKH + w * 1024);
    ld_g2l16(wkh + bbase + 512, BKH + w * 1024 + 512);
    ld_g2l16(wkl + bbase, BKL + w * 1024);
    ld_g2l16(wkl + bbase + 512, BKL + w * 1024 + 512);
    // --- A: f32 regs -> f16 hi/lo chunks, lane-sequential writes ---
    {
      float av0[8] = {f0.x, f0.y, f0.z, f0.w, f1.x, f1.y, f1.z, f1.w};
      float av1[8] = {f2.x, f2.y, f2.z, f2.w, f3.x, f3.y, f3.z, f3.w};
      half8 h0, h1, l0, l1;
#pragma unroll
      for (int j = 0; j < 8; ++j) {
        _Float16 a = (_Float16)av0[j];
        h0[j] = a;
        l0[j] = (_Float16)(av0[j] - (float)a);
        _Float16 b = (_Float16)av1[j];
        h1[j] = b;
        l1[j] = (_Float16)(av1[j] - (float)b);
      }
      *(half8*)(AH + tid * 8) = h0;
      *(half8*)(AH + (tid + 256) * 8) = h1;
      *(half8*)(AL + tid * 8) = l0;
      *(half8*)(AL + (tid + 256) * 8) = l1;
    }
    __syncthreads();
    if (kt < 15) {
      const float* xp = ap + (kt + 1) * 32;
      f0 = *(const float4*)(xp);
      f1 = *(const float4*)(xp + 4);
      f2 = *(const float4*)(xp + 64 * 512);
      f3 = *(const float4*)(xp + 64 * 512 + 4);
    }
    // --- A fragments (shared by both GEMMs) ---
    half8 ah[4], al[4];
#pragma unroll
    for (int mb = 0; mb < 4; ++mb) {
      const int cm = wrow * 4 + mb;
      ah[mb] = *(const half8*)(AH + (cm * 64 + lane) * 8);
      al[mb] = *(const half8*)(AL + (cm * 64 + lane) * 8);
    }
    // --- Q side ---
    {
      half8 bh[4], bl[4];
#pragma unroll
      for (int nb = 0; nb < 4; ++nb) {
        bh[nb] = *(const half8*)(BQH + ((wcol * 4 + nb) * 64 + lane) * 8);
        bl[nb] = *(const half8*)(BQL + ((wcol * 4 + nb) * 64 + lane) * 8);
      }
#pragma unroll
      for (int nb = 0; nb < 4; ++nb)
#pragma unroll
        for (int mb = 0; mb < 4; ++mb) {
          accq[mb][nb] = __builtin_amdgcn_mfma_f32_16x16x32_f16(ah[mb], bh[nb], accq[mb][nb], 0, 0, 0);
          accq[mb][nb] = __builtin_amdgcn_mfma_f32_16x16x32_f16(al[mb], bh[nb], accq[mb][nb], 0, 0, 0);
          accq[mb][nb] = __builtin_amdgcn_mfma_f32_16x16x32_f16(ah[mb], bl[nb], accq[mb][nb], 0, 0, 0);
        }
    }
    // --- K side (reuse b-frag registers) ---
    {
      half8 bh[4], bl[4];
#pragma unroll
      for (int nb = 0; nb < 4; ++nb) {
        bh[nb] = *(const half8*)(BKH + ((wcol * 4 + nb) * 64 + lane) * 8);
        bl[nb] = *(const half8*)(BKL + ((wcol * 4 + nb) * 64 + lane) * 8);
      }
#pragma unroll
      for (int nb = 0; nb < 4; ++nb)
#pragma unroll
        for (int mb = 0; mb < 4; ++mb) {
          acck[mb][nb] = __builtin_amdgcn_mfma_f32_16x16x32_f16(ah[mb], bh[nb], acck[mb][nb], 0, 0, 0);
          acck[mb][nb] = __builtin_amdgcn_mfma_f32_16x16x32_f16(al[mb], bh[nb], acck[mb][nb], 0, 0, 0);
          acck[mb][nb] = __builtin_amdgcn_mfma_f32_16x16x32_f16(ah[mb], bl[nb], acck[mb][nb], 0, 0, 0);
        }
    }
    __syncthreads();
  }

  // ---------------- epilogue ----------------
  // k-acc -> LDS (f16), row-major stride 136 halfs (=272 B) so the 4 g-rows
  // of a read/write group land on different banks. 128*136*2 B = 34 KB.
  _Float16* KX = smem;
  const int col0 = wcol * 64 + n;
  const int rbase = wrow * 64;
#pragma unroll
  for (int mb = 0; mb < 4; ++mb)
#pragma unroll
    for (int reg = 0; reg < 4; ++reg) {
      const int rl = rbase + mb * 16 + g * 4 + reg;
#pragma unroll
      for (int nb = 0; nb < 4; ++nb)
        KX[rl * 136 + col0 + nb * 16] = (_Float16)acck[mb][nb][reg];
    }
  __syncthreads();

  // block-boundary edges: k local row 127 and q local row 0 (f32, 128 cols
  // per (rb,cb) block -> full 512 cols per rb across cb).
  if (wrow == 1 && g == 3) {
#pragma unroll
    for (int nb = 0; nb < 4; ++nb)
      kedge[rb * 512 + cb * 128 + col0 + nb * 16] = acck[3][nb][3];
  }
  if (wrow == 0 && g == 0) {
#pragma unroll
    for (int nb = 0; nb < 4; ++nb)
      qedge[rb * 512 + cb * 128 + col0 + nb * 16] = accq[0][nb][0];
  }

  // per-row partials: ssq, ssk, dot = q[r] . k[r-1] (k from LDS, f16 like
  // the old kbuf path). Local row 0's dot comes from edgedot.
#pragma unroll
  for (int mb = 0; mb < 4; ++mb) {
#pragma unroll
    for (int reg = 0; reg < 4; ++reg) {
      const int rl = rbase + mb * 16 + g * 4 + reg;
      const long row = r0 + rl;
      float sq = 0.f, sk = 0.f, dt = 0.f;
#pragma unroll
      for (int nb = 0; nb < 4; ++nb) {
        float qv = accq[mb][nb][reg];
        float kv = acck[mb][nb][reg];
        sq = fmaf(qv, qv, sq);
        sk = fmaf(kv, kv, sk);
        if (rl > 0) {
          float kp = (float)KX[(rl - 1) * 136 + col0 + nb * 16];
          dt = fmaf(qv, kp, dt);
        }
      }
#pragma unroll
      for (int m = 1; m < 16; m <<= 1) {
        sq += __shfl_xor(sq, m, 64);
        sk += __shfl_xor(sk, m, 64);
        dt += __shfl_xor(dt, m, 64);
      }
      if (n == 0) {
        atomicAdd(&ssqOut[row], sq);
        atomicAdd(&sskOut[row], sk);
        if (rl > 0) atomicAdd(&dotOut[row], dt);
      }
    }
  }
}

// ---------------------------------------------------------------------------
// Boundary rows (r multiple of 128, r's l != 0): dot = qedge[rb] . kedge[rb-1]
// over all 512 cols. Sole writer of dotOut for these rows.
// ---------------------------------------------------------------------------
__global__ __launch_bounds__(64) void edgedot(
    const float* __restrict__ qedge, const float* __restrict__ kedge,
    float* __restrict__ dotOut) {
  const int rb = blockIdx.x;  // 0..511
  if (rb == 0) return;
  const long row = (long)rb * 128;
  if ((row & (LL - 1)) == 0) return;  // l == 0: p forced to 1, dot unused
  const int lane = threadIdx.x;
  float dt = 0.f;
#pragma unroll
  for (int c = lane; c < 512; c += 64)
    dt = fmaf(qedge[rb * 512 + c], kedge[(rb - 1) * 512 + c], dt);
#pragma unroll
  for (int m = 1; m < 64; m <<= 1) dt += __shfl_xor(dt, m, 64);
  if (lane == 0) dotOut[row] = dt;
}

// ---------------------------------------------------------------------------
// Combine: cos from partials -> p, b_hard, fixlist.
// ---------------------------------------------------------------------------
__global__ __launch_bounds__(256) void combine(
    const float* __restrict__ ssq, const float* __restrict__ ssk,
    const float* __restrict__ dotb, float* __restrict__ dout,
    int* __restrict__ fixlist, int* __restrict__ fixcnt) {
  const int r = blockIdx.x * 256 + threadIdx.x;
  const int l = r & (LL - 1);
  float p;
  float cosv = 0.0f;
  if (l != 0) {
    float nq = fmaxf(sqrtf(ssq[r]), 1e-12f);
    float nk = fmaxf(sqrtf(ssk[r - 1]), 1e-12f);
    cosv = dotb[r] / (nq * nk);
    p = fminf(fmaxf(0.5f * (1.0f - cosv), 0.0f), 1.0f);
  } else {
    p = 1.0f;
  }
  dout[OUT_P + r] = p;
  dout[OUT_BHARD + r] = (p >= 0.5f) ? 1.0f : 0.0f;
  if (l != 0 && fabsf(cosv) < FIX_TAU) {
    int idx = atomicAdd(fixcnt, 1);
    if (idx < FIX_CAP) fixlist[idx] = r;
  }
}

// ---------------------------------------------------------------------------
// f64 recompute of borderline rows (expected ~120 rows at TAU=1e-4).
// ---------------------------------------------------------------------------
__global__ __launch_bounds__(256) void fixup(
    const float* __restrict__ x, const float* __restrict__ Wq,
    const float* __restrict__ Wk, float* __restrict__ dout,
    const int* __restrict__ fixlist, const int* __restrict__ fixcnt) {
  __shared__ float xr[512], xp[512];
  __shared__ double red[3][256];
  const int t = threadIdx.x;
  int nfix = *fixcnt;
  if (nfix > FIX_CAP) nfix = FIX_CAP;

  for (int idx = blockIdx.x; idx < nfix; idx += gridDim.x) {
    const int r = fixlist[idx];
    for (int d = t; d < 512; d += 256) {
      xr[d] = x[(long)r * 512 + d];
      xp[d] = x[(long)(r - 1) * 512 + d];
    }
    __syncthreads();
    double ssq = 0.0, ssk = 0.0, dot = 0.0;
    for (int e = t; e < 512; e += 256) {
      const float* wq = Wq + (long)e * 512;
      const float* wk = Wk + (long)e * 512;
      double q = 0.0, k = 0.0;
      for (int d = 0; d < 512; ++d) {
        q = fma((double)xr[d], (double)wq[d], q);
        k = fma((double)xp[d], (double)wk[d], k);
      }
      ssq += q * q;
      ssk += k * k;
      dot += q * k;
    }
    red[0][t] = ssq;
    red[1][t] = ssk;
    red[2][t] = dot;
    __syncthreads();
    for (int s = 128; s > 0; s >>= 1) {
      if (t < s) {
        red[0][t] += red[0][t + s];
        red[1][t] += red[1][t + s];
        red[2][t] += red[2][t + s];
      }
      __syncthreads();
    }
    if (t == 0) {
      double nq = sqrt(red[0][0]);
      double nk = sqrt(red[1][0]);
      if (nq < 1e-12) nq = 1e-12;
      if (nk < 1e-12) nk = 1e-12;
      float c = (float)(red[2][0] / (nq * nk));
      float p = fminf(fmaxf(0.5f * (1.0f - c), 0.0f), 1.0f);
      dout[OUT_P + r] = p;
      dout[OUT_BHARD + r] = (p >= 0.5f) ? 1.0f : 0.0f;
    }
    __syncthreads();
  }
}

// ---------------------------------------------------------------------------
// Per-batch scan (shfl-based), mask, p_compressed, sel, counts.
// ---------------------------------------------------------------------------
__global__ __launch_bounds__(256) void scanb(
    float* __restrict__ dout, int* __restrict__ sel,
    int* __restrict__ counts, float* __restrict__ sump) {
  __shared__ int wtot[4];
  __shared__ float wps[4];
  const int b = blockIdx.x;
  const int t = threadIdx.x;
  const int lane = t & 63, wv = t >> 6;
  const long base = (long)b * LL;

  int cnt = 0;
  float psum = 0.0f;
#pragma unroll 4
  for (int j = 0; j < 32; ++j) {
    int l = t * 32 + j;
    float bh = dout[OUT_BHARD + base + l];
    float pv = dout[OUT_P + base + l];
    cnt += (bh > 0.5f) ? 1 : 0;
    psum += pv;
  }
  int inc = cnt;
#pragma unroll
  for (int off = 1; off < 64; off <<= 1) {
    int u = __shfl_up(inc, off, 64);
    if (lane >= off) inc += u;
  }
  float ps = psum;
#pragma unroll
  for (int off = 1; off < 64; off <<= 1) ps += __shfl_xor(ps, off, 64);
  if (lane == 63) wtot[wv] = inc;
  if (lane == 0) wps[wv] = ps;
  __syncthreads();
  int wbase = 0, total = 0;
#pragma unroll
  for (int i = 0; i < 4; ++i) {
    int c = wtot[i];
    if (i < wv) wbase += c;
    total += c;
  }
  if (t == 0) {
    counts[b] = total;
    sump[b] = wps[0] + wps[1] + wps[2] + wps[3];
  }
  for (int j = 0; j < 32; ++j) {
    int l = t * 32 + j;
    dout[OUT_MASK + base + l] = (l < total) ? 1.0f : 0.0f;
    dout[OUT_PCOMP + base + l] = 0.0f;
  }
  __syncthreads();
  int pos = wbase + inc - cnt;  // exclusive prefix
  for (int j = 0; j < 32; ++j) {
    int l = t * 32 + j;
    float bh = dout[OUT_BHARD + base + l];
    if (bh > 0.5f) {
      dout[OUT_PCOMP + base + pos] = dout[OUT_P + base + l];
      sel[base + pos] = l;
      ++pos;
    }
  }
}

// ---------------------------------------------------------------------------
__global__ void lossk(float* __restrict__ dout, const int* __restrict__ counts,
                      const float* __restrict__ sump) {
  if (threadIdx.x == 0 && blockIdx.x == 0) {
    float fc = 0.0f, gs = 0.0f;
    for (int b = 0; b < BB; ++b) {
      fc += (float)counts[b];
      gs += sump[b];
    }
    float F = fc / (float)NROWS;
    float G = gs / (float)NROWS;
    dout[OUT_LOSS] = 1.2f * (5.0f * F * G + (1.0f - F) * (1.0f - G));
  }
}

// ---------------------------------------------------------------------------
__global__ __launch_bounds__(128) void emit(
    const float* __restrict__ x, float* __restrict__ dout,
    const int* __restrict__ sel, const int* __restrict__ counts) {
  const long bid = blockIdx.x;
  const int b = (int)(bid >> 13);
  const int j = (int)(bid & (LL - 1));
  const int cnt = counts[b];
  float4 v = make_float4(0.0f, 0.0f, 0.0f, 0.0f);
  if (j < cnt) {
    const int l = sel[((long)b << 13) + j];
    v = *(const float4*)(x + (((long)b << 13) + l) * 512 + threadIdx.x * 4);
  }
  *(float4*)(dout + OUT_COMP + (((long)b << 13) + j) * 512 + threadIdx.x * 4) = v;
}

// ---------------------------------------------------------------------------
extern "C" void kernel_launch(void* const* d_in, const int* in_sizes, int n_in,
                              void* d_out, int out_size, void* d_ws,
                              size_t ws_size, hipStream_t stream) {
  const float* x = (const float*)d_in[0];
  const float* Wq = (const float*)d_in[1];
  const float* Wk = (const float*)d_in[2];
  float* out = (float*)d_out;
  char* ws = (char*)d_ws;

  int* fixlist = (int*)(ws + WS_FIXLIST);
  int* fixcnt = (int*)(ws + WS_FIXCNT);
  int* counts = (int*)(ws + WS_COUNTS);
  float* sump = (float*)(ws + WS_SUMP);
  int* sel = (int*)(ws + WS_SEL);
  float* ssk = (float*)(ws + WS_SSK);
  float* ssq = (float*)(ws + WS_SSQ);
  float* dotb = (float*)(ws + WS_DOT);
  _Float16* wqh = (_Float16*)(ws + WS_WQH);
  _Float16* wql = (_Float16*)(ws + WS_WQL);
  _Float16* wkh = (_Float16*)(ws + WS_WKH);
  _Float16* wkl = (_Float16*)(ws + WS_WKL);

  // edge buffers (512x512 f32 each = 1 MB) staged in d_out's compressed
  // region; emit overwrites it at the end.
  float* kedge = (float*)(out + OUT_COMP);
  float* qedge = (float*)(out + OUT_COMP + 262144);

  wsplit<<<256, 256, 0, stream>>>(Wq, Wk, wqh, wql, wkh, wkl, ssk, ssq, dotb, fixcnt);
  gemm_fused<<<2048, 256, 0, stream>>>(x, wqh, wql, wkh, wkl, ssq, ssk, dotb, qedge, kedge);
  edgedot<<<512, 64, 0, stream>>>(qedge, kedge, dotb);
  combine<<<NROWS / 256, 256, 0, stream>>>(ssq, ssk, dotb, out, fixlist, fixcnt);
  fixup<<<512, 256, 0, stream>>>(x, Wq, Wk, out, fixlist, fixcnt);
  scanb<<<BB, 256, 0, stream>>>(out, sel, counts, sump);
  lossk<<<1, 64, 0, stream>>>(out, counts, sump);
  emit<<<NROWS, 128, 0, stream>>>(x, out, sel, counts);
}